// Round 1
// baseline (436.548 us; speedup 1.0000x reference)
//
#include <hip/hip_runtime.h>
#include <math.h>

#define B   32
#define T   2048
#define H   1024
#define OUTD 256
#define NC  32     // t-chunks in fused kernel (chunk = 64 rows)
#define KC1 16     // k-chunks in k1a (chunk = 64)

// ---------------- k1a: partial h_t = hs[:, T-1, :] @ W1 (k-split partials) ----
__global__ __launch_bounds__(256) void k1a_partial_ht(
    const float* __restrict__ hs, const float* __restrict__ W1,
    float* __restrict__ ph)
{
    const int tid = threadIdx.x;
    const int h   = blockIdx.x * 256 + tid;   // 4 h-tiles
    const int k0  = blockIdx.y * 64;          // 16 k-chunks

    __shared__ float s_hs[B][64];
    for (int it = 0; it < 8; ++it) {
        int idx = tid + it * 256;
        int b = idx >> 6, k = idx & 63;
        s_hs[b][k] = hs[((size_t)(b * T + (T - 1)) << 10) + k0 + k];
    }
    __syncthreads();

    float acc[B];
#pragma unroll
    for (int b = 0; b < B; ++b) acc[b] = 0.f;

    for (int k4 = 0; k4 < 16; ++k4) {
        float w0 = W1[(size_t)(k0 + k4 * 4 + 0) * H + h];
        float w1 = W1[(size_t)(k0 + k4 * 4 + 1) * H + h];
        float w2 = W1[(size_t)(k0 + k4 * 4 + 2) * H + h];
        float w3 = W1[(size_t)(k0 + k4 * 4 + 3) * H + h];
#pragma unroll
        for (int b = 0; b < B; ++b) {
            const float4 hv = *(const float4*)&s_hs[b][k4 * 4];
            acc[b] = fmaf(hv.x, w0, acc[b]);
            acc[b] = fmaf(hv.y, w1, acc[b]);
            acc[b] = fmaf(hv.z, w2, acc[b]);
            acc[b] = fmaf(hv.w, w3, acc[b]);
        }
    }
    float* dst = ph + ((size_t)blockIdx.y * B << 10);
#pragma unroll
    for (int b = 0; b < B; ++b) dst[((size_t)b << 10) + h] = acc[b];
}

// ---------------- k1b: h_t = sum(partials) + b1 ------------------------------
__global__ __launch_bounds__(256) void k1b_reduce_ht(
    const float* __restrict__ ph, const float* __restrict__ b1,
    float* __restrict__ h_t)
{
    int i = blockIdx.x * 256 + threadIdx.x;   // 0..B*H-1 (i = b*H + h)
    int h = i & (H - 1);
    float s = b1[h];
#pragma unroll
    for (int c = 0; c < KC1; ++c)
        s += ph[((size_t)c * B << 10) + i];
    h_t[i] = s;
}

// ---------------- k2: u[b,k] = dot(W1[k,:], h_t[b,:]) ------------------------
__global__ __launch_bounds__(256) void k2_compute_u(
    const float* __restrict__ W1, const float* __restrict__ h_t,
    float* __restrict__ u)
{
    const int wid  = threadIdx.x >> 6;
    const int lane = threadIdx.x & 63;
    const int k    = blockIdx.x * 4 + wid;    // 256 blocks x 4 waves = 1024 k
    const float4* wr = (const float4*)(W1 + ((size_t)k << 10));
    float4 wq[4];
#pragma unroll
    for (int j = 0; j < 4; ++j) wq[j] = wr[lane + 64 * j];

    for (int b = 0; b < B; ++b) {
        const float4* hr = (const float4*)(h_t + ((size_t)b << 10));
        float s = 0.f;
#pragma unroll
        for (int j = 0; j < 4; ++j) {
            float4 hv = hr[lane + 64 * j];
            s += wq[j].x * hv.x + wq[j].y * hv.y + wq[j].z * hv.z + wq[j].w * hv.w;
        }
#pragma unroll
        for (int off = 32; off; off >>= 1) s += __shfl_xor(s, off, 64);
        if (lane == 0) u[((size_t)b << 10) + k] = s;
    }
}

// ---------------- k3: fused score + online softmax + weighted pooling --------
__global__ __launch_bounds__(256) void k3_fused(
    const float* __restrict__ hs, const float* __restrict__ u,
    float* __restrict__ ctx_p, float* __restrict__ m_p, float* __restrict__ l_p)
{
    const int c    = blockIdx.x;          // t-chunk (0..31)
    const int b    = blockIdx.y;          // batch
    const int w    = threadIdx.x >> 6;    // wave 0..3
    const int lane = threadIdx.x & 63;
    const int tid  = threadIdx.x;

    const float4* urow = (const float4*)(u + ((size_t)b << 10));
    float4 uq[4];
#pragma unroll
    for (int j = 0; j < 4; ++j) uq[j] = urow[lane + 64 * j];

    const int t0 = c * 64 + w * 16;       // 16 rows per wave
    const float4* xrow = (const float4*)(hs + ((size_t)(b * T + t0) << 10));

    float m = -INFINITY, lsum = 0.f;
    float4 acc[4];
#pragma unroll
    for (int j = 0; j < 4; ++j) acc[j] = make_float4(0.f, 0.f, 0.f, 0.f);

    float4 x[4], y[4];
#pragma unroll
    for (int j = 0; j < 4; ++j) x[j] = xrow[lane + 64 * j];

    for (int r = 0; r < 16; ++r) {
        const float4* nrow = xrow + 256;
        if (r < 15) {
#pragma unroll
            for (int j = 0; j < 4; ++j) y[j] = nrow[lane + 64 * j];
        }
        float s = 0.f;
#pragma unroll
        for (int j = 0; j < 4; ++j)
            s += x[j].x * uq[j].x + x[j].y * uq[j].y + x[j].z * uq[j].z + x[j].w * uq[j].w;
#pragma unroll
        for (int off = 32; off; off >>= 1) s += __shfl_xor(s, off, 64);

        float mn = fmaxf(m, s);
        float al = __expf(m - mn);     // exp(-inf)=0 on first row
        float wt = __expf(s - mn);
        lsum = lsum * al + wt;
#pragma unroll
        for (int j = 0; j < 4; ++j) {
            acc[j].x = fmaf(acc[j].x, al, wt * x[j].x);
            acc[j].y = fmaf(acc[j].y, al, wt * x[j].y);
            acc[j].z = fmaf(acc[j].z, al, wt * x[j].z);
            acc[j].w = fmaf(acc[j].w, al, wt * x[j].w);
        }
        m = mn;
#pragma unroll
        for (int j = 0; j < 4; ++j) x[j] = y[j];
        xrow = nrow;
    }

    // ---- combine 4 waves within block ----
    __shared__ float sm[4], sl[4];
    __shared__ float sacc[4][H];          // 16 KB
    if (lane == 0) { sm[w] = m; sl[w] = lsum; }
    __syncthreads();
    const float mp = fmaxf(fmaxf(sm[0], sm[1]), fmaxf(sm[2], sm[3]));
    const float alw = __expf(m - mp);
    float4* sa = (float4*)&sacc[w][0];
#pragma unroll
    for (int j = 0; j < 4; ++j) {
        float4 v;
        v.x = acc[j].x * alw; v.y = acc[j].y * alw;
        v.z = acc[j].z * alw; v.w = acc[j].w * alw;
        sa[lane + 64 * j] = v;
    }
    __syncthreads();
    float lp = 0.f;
#pragma unroll
    for (int ww = 0; ww < 4; ++ww) lp += sl[ww] * __expf(sm[ww] - mp);

    float* dst = ctx_p + (((size_t)b * NC + c) << 10);
#pragma unroll
    for (int i = 0; i < 4; ++i) {
        int h = tid + 256 * i;
        dst[h] = sacc[0][h] + sacc[1][h] + sacc[2][h] + sacc[3][h];
    }
    if (tid == 0) { m_p[b * NC + c] = mp; l_p[b * NC + c] = lp; }
}

// ---------------- k4: combine chunk partials; build pre = [ctx, h_t] ---------
__global__ __launch_bounds__(256) void k4_combine(
    const float* __restrict__ ctx_p, const float* __restrict__ m_p,
    const float* __restrict__ l_p, const float* __restrict__ h_t,
    float* __restrict__ pre)
{
    const int b   = blockIdx.x;
    const int tid = threadIdx.x;
    __shared__ float e[NC];
    float M = -INFINITY;
    for (int c = 0; c < NC; ++c) M = fmaxf(M, m_p[b * NC + c]);
    float L = 0.f;
    for (int c = 0; c < NC; ++c) L += l_p[b * NC + c] * __expf(m_p[b * NC + c] - M);
    if (tid < NC) e[tid] = __expf(m_p[b * NC + tid] - M);
    __syncthreads();
    const float inv = 1.f / L;
#pragma unroll
    for (int i = 0; i < 4; ++i) {
        int h = tid + 256 * i;
        float s = 0.f;
#pragma unroll
        for (int c = 0; c < NC; ++c)
            s += ctx_p[(((size_t)b * NC + c) << 10) + h] * e[c];
        pre[((size_t)b << 11) + h] = s * inv;
        pre[((size_t)b << 11) + H + h] = h_t[((size_t)b << 10) + h];
    }
}

// ---------------- k5a: pre @ Wv, k-split with atomic accumulate --------------
__global__ __launch_bounds__(256) void k5a_matmul(
    const float* __restrict__ pre, const float* __restrict__ Wv,
    float* __restrict__ accum)
{
    const int kc = blockIdx.x;   // 0..7 (k-chunk of 256)
    const int b  = blockIdx.y;
    const int o  = threadIdx.x;
    __shared__ float sp[256];
    sp[o] = pre[((size_t)b << 11) + kc * 256 + o];
    __syncthreads();
    float acc = 0.f;
    const float* wv = Wv + (size_t)kc * 256 * OUTD + o;
#pragma unroll 8
    for (int k = 0; k < 256; ++k)
        acc = fmaf(sp[k], wv[(size_t)k * OUTD], acc);
    atomicAdd(&accum[b * OUTD + o], acc);
}

// ---------------- k5b: out = tanh(accum + bv) --------------------------------
__global__ __launch_bounds__(256) void k5b_tanh(
    const float* __restrict__ accum, const float* __restrict__ bv,
    float* __restrict__ out)
{
    int i = blockIdx.x * 256 + threadIdx.x;
    out[i] = tanhf(accum[i] + bv[i & (OUTD - 1)]);
}

extern "C" void kernel_launch(void* const* d_in, const int* in_sizes, int n_in,
                              void* d_out, int out_size, void* d_ws, size_t ws_size,
                              hipStream_t stream)
{
    const float* hs = (const float*)d_in[0];
    const float* W1 = (const float*)d_in[1];
    const float* b1 = (const float*)d_in[2];
    const float* Wv = (const float*)d_in[3];
    const float* bv = (const float*)d_in[4];
    float* out = (float*)d_out;
    float* ws  = (float*)d_ws;

    float* ph    = ws;                              // KC1*B*H  = 524288 floats
    float* h_t   = ph + (size_t)KC1 * B * H;        // B*H      = 32768
    float* u     = h_t + (size_t)B * H;             // B*H      = 32768
    float* m_p   = u + (size_t)B * H;               // B*NC     = 1024
    float* l_p   = m_p + B * NC;                    // B*NC     = 1024
    float* ctx_p = l_p + B * NC;                    // B*NC*H   = 1048576
    float* pre   = ctx_p + (size_t)B * NC * H;      // B*2H     = 65536
    float* accum = pre + (size_t)B * 2 * H;         // B*OUTD   = 8192
    // total ~6.9 MB of d_ws

    hipMemsetAsync(accum, 0, B * OUTD * sizeof(float), stream);

    k1a_partial_ht<<<dim3(4, KC1), 256, 0, stream>>>(hs, W1, ph);
    k1b_reduce_ht<<<(B * H) / 256, 256, 0, stream>>>(ph, b1, h_t);
    k2_compute_u<<<H / 4, 256, 0, stream>>>(W1, h_t, u);
    k3_fused<<<dim3(NC, B), 256, 0, stream>>>(hs, u, ctx_p, m_p, l_p);
    k4_combine<<<B, 256, 0, stream>>>(ctx_p, m_p, l_p, h_t, pre);
    k5a_matmul<<<dim3(8, B), 256, 0, stream>>>(pre, Wv, accum);
    k5b_tanh<<<B, 256, 0, stream>>>(accum, bv, out);
}